// Round 19
// baseline (245.573 us; speedup 1.0000x reference)
//
#include <hip/hip_runtime.h>
#include <hip/hip_fp16.h>

// MHA forward, fp16 MFMA pipeline.
// B=2, N=4096, E=768, H=8, D=96.  SCALE applied AFTER softmax (faithful to ref).
// Round 19: R18 (best, 244.6us) with the redundant per-tile barrier removed:
//   double-buffer invariant proves writes to kvbuf[cur^1] in iter t can't race
//   any reads (last reads of cur^1 were in iter t-1, gated by that iter's
//   barrier). ds_writes hoisted after V->regs to overlap softmax/PV.
//   One barrier per tile instead of two. GEMM/prep identical to R18.

typedef _Float16 half8 __attribute__((ext_vector_type(8)));
typedef _Float16 half4 __attribute__((ext_vector_type(4)));
typedef float   float4_ __attribute__((ext_vector_type(4)));
typedef float   f32x16 __attribute__((ext_vector_type(16)));

#define SCALE 0.102062072615966f  // 96^-0.5
#define LOG2E 1.44269504088896340736f

__device__ __forceinline__ float4_ mfma16(half8 a, half8 b, float4_ c) {
    return __builtin_amdgcn_mfma_f32_16x16x32_f16(a, b, c, 0, 0, 0);
}
__device__ __forceinline__ f32x16 mfma32(half8 a, half8 b, f32x16 c) {
    return __builtin_amdgcn_mfma_f32_32x32x16_f16(a, b, c, 0, 0, 0);
}
__device__ __forceinline__ void gload16(const _Float16* g, _Float16* l) {
    __builtin_amdgcn_global_load_lds(
        (const __attribute__((address_space(1))) void*)g,
        (__attribute__((address_space(3))) void*)l, 16, 0, 0);
}

// Raw v_exp_f32: single transcendental, no denormal-guard sequence (R10-verified).
__device__ __forceinline__ float fast_exp2(float x) {
#if __has_builtin(__builtin_amdgcn_exp2f)
    return __builtin_amdgcn_exp2f(x);
#else
    float r;
    asm("v_exp_f32 %0, %1" : "=v"(r) : "v"(x));
    return r;
#endif
}

// Packed f32 pair -> f16x2 in one VALU op (RTZ; fine at 1e-2 tol).
__device__ __forceinline__ uint32_t pack_pair(float a, float b) {
#if __has_builtin(__builtin_amdgcn_cvt_pkrtz)
    auto h = __builtin_amdgcn_cvt_pkrtz(a, b);
    union { decltype(h) v; uint32_t u; } c;
    c.v = h;
    return c.u;
#else
    union { _Float16 h[2]; uint32_t u; } c;
    c.h[0] = (_Float16)a; c.h[1] = (_Float16)b;
    return c.u;
#endif
}

// ---------------- fused prep kernel ----------------
// blocks [0,6144): cast x -> f16.  [6144,6720): W transpose.  [6720,6729): bias concat.
__global__ void prep_all(const float* __restrict__ x, _Float16* __restrict__ xb,
                         const float* __restrict__ Wq, const float* __restrict__ Wk,
                         const float* __restrict__ Wv, const float* __restrict__ Wo,
                         _Float16* __restrict__ wqkv, _Float16* __restrict__ wot,
                         const float* __restrict__ bq, const float* __restrict__ bk,
                         const float* __restrict__ bv, float* __restrict__ bqkv) {
    __shared__ float tile[64][65];
    const int bid = blockIdx.x;
    const int t = threadIdx.x;
    if (bid < 6144) {                       // cast_x: 6144*256 float4 = 8192*768 floats
        int i = bid * 256 + t;
        float4_ v = ((const float4_*)x)[i];
        half4 h = { (_Float16)v[0], (_Float16)v[1], (_Float16)v[2], (_Float16)v[3] };
        ((half4*)xb)[i] = h;
    } else if (bid < 6720) {                // prep_w: 576 = 4 mats * 12 * 12
        const int wb = bid - 6144;
        const int mat = wb / 144, rem = wb % 144;
        const int kt = rem / 12, ct = rem % 12;
        const float* W = (mat == 0) ? Wq : (mat == 1) ? Wk : (mat == 2) ? Wv : Wo;
        const int k0 = kt * 64, c0 = ct * 64;
        const int lr = t >> 4, lc = (t & 15) * 4;
        #pragma unroll
        for (int i = 0; i < 4; ++i) {
            float4_ v = *(const float4_*)(W + (size_t)(k0 + i * 16 + lr) * 768 + c0 + lc);
            tile[i * 16 + lr][lc + 0] = v[0];
            tile[i * 16 + lr][lc + 1] = v[1];
            tile[i * 16 + lr][lc + 2] = v[2];
            tile[i * 16 + lr][lc + 3] = v[3];
        }
        __syncthreads();
        const int cr = t >> 2, kq = (t & 3) * 16;
        _Float16* dst = (mat < 3) ? (wqkv + ((size_t)(mat * 768 + c0 + cr)) * 768 + k0 + kq)
                                  : (wot  + ((size_t)(c0 + cr)) * 768 + k0 + kq);
        half8 h0, h1;
        #pragma unroll
        for (int j = 0; j < 8; ++j) {
            h0[j] = (_Float16)tile[kq + j][cr];
            h1[j] = (_Float16)tile[kq + 8 + j][cr];
        }
        *(half8*)dst = h0;
        *(half8*)(dst + 8) = h1;
    } else {                                // prep_bias: 9 blocks -> 2304 floats
        int i = (bid - 6720) * 256 + t;
        float v = (i < 768) ? bq[i] : (i < 1536) ? bk[i - 768] : bv[i - 1536];
        bqkv[i] = v;
    }
}

// ---------------- GEMM: C = A(8192x768) @ Bt^T + bias, 128x128 tile, BK=64 ----
__global__ __launch_bounds__(256, 2) void gemm_kernel(
    const _Float16* __restrict__ A, const _Float16* __restrict__ Bt,
    const float* __restrict__ bias, int mode,
    _Float16* __restrict__ Qo, _Float16* __restrict__ Ko, _Float16* __restrict__ Vto,
    float* __restrict__ out)
{
    __shared__ alignas(16) _Float16 Af[16 * 512];   // 16 frags (mi 0..7, kc 0..1)
    __shared__ alignas(16) _Float16 Bf[16 * 512];
    const int tid = threadIdx.x;
    const int lane = tid & 63, w = tid >> 6;
    const int wm = w >> 1, wn = w & 1;
    const int l15 = lane & 15, l4 = lane >> 4;
    const int m0 = blockIdx.y * 128;
    const int n0 = blockIdx.x * 128;

    const _Float16* gs[8];
    _Float16* ld[8];
    #pragma unroll
    for (int i = 0; i < 8; ++i) {
        int f = (w & 1) * 8 + i;
        int rg = f >> 1, kc = f & 1;
        int r0 = ((w < 2) ? m0 : n0) + rg * 16;
        gs[i] = ((w < 2) ? A : Bt) + (size_t)(r0 + l15) * 768 + kc * 32 + l4 * 8;
        ld[i] = ((w < 2) ? Af : Bf) + f * 512;
    }

    float4_ acc[4][4] = {};

    for (int k0 = 0; k0 < 768; k0 += 64) {
        #pragma unroll
        for (int i = 0; i < 8; ++i)
            gload16(gs[i] + k0, ld[i]);
        __syncthreads();
        #pragma unroll
        for (int kc = 0; kc < 2; ++kc) {
            half8 bfr[4];
            #pragma unroll
            for (int nt = 0; nt < 4; ++nt)
                bfr[nt] = *(const half8*)(Bf + (size_t)(((wn * 4 + nt) * 2 + kc) * 512 + lane * 8));
            #pragma unroll
            for (int mt = 0; mt < 4; ++mt) {
                half8 afr = *(const half8*)(Af + (size_t)(((wm * 4 + mt) * 2 + kc) * 512 + lane * 8));
                #pragma unroll
                for (int nt = 0; nt < 4; ++nt)
                    acc[mt][nt] = mfma16(afr, bfr[nt], acc[mt][nt]);
            }
        }
        __syncthreads();
    }

    #pragma unroll
    for (int mt = 0; mt < 4; ++mt)
    #pragma unroll
    for (int nt = 0; nt < 4; ++nt) {
        int gc = n0 + wn * 64 + nt * 16 + l15;
        float bv_ = bias[gc];
        #pragma unroll
        for (int r = 0; r < 4; ++r) {
            int gm = m0 + wm * 64 + mt * 16 + l4 * 4 + r;
            float val = acc[mt][nt][r] + bv_;
            if (mode == 1) {
                out[(size_t)gm * 768 + gc] = val;
            } else {
                int b = gm >> 12, n = gm & 4095;
                if (gc < 768) {
                    int h = gc / 96, d = gc % 96;
                    Qo[(((size_t)(b * 8 + h)) * 4096 + n) * 96 + d] = (_Float16)(val * LOG2E);
                } else if (gc < 1536) {
                    int c = gc - 768, h = c / 96, d = c % 96;
                    int bh = b * 8 + h;
                    size_t idx = (((size_t)bh * 128 + (n >> 5)) * 6 + (d >> 4)) * 512
                               + (size_t)((d >> 3) & 1) * 256 + (size_t)(n & 31) * 8 + (d & 7);
                    Ko[idx] = (_Float16)val;
                } else {
                    int c = gc - 1536, h = c / 96, d = c % 96;
                    int bh = b * 8 + h;
                    size_t idx = (((size_t)bh * 64 + (n >> 6)) * 12 + ((n >> 4) & 3) * 3 + (d >> 5)) * 512
                               + (size_t)((n >> 3) & 1) * 256 + (size_t)(d & 31) * 8 + (n & 7);
                    Vto[idx] = (_Float16)val;
                }
            }
        }
    }
}

// ---------------- flash attention: 4 waves x 32 q, KV tile 64 ----------------
// 512 blocks (2/CU, 2 waves/SIMD). Single barrier per tile (double-buffer
// invariant: iter t's writes to kvbuf[cur^1] can't race — its last reads were
// in iter t-1, gated by that iter's barrier). Per tile:
//   [issue next-tile global->regs] [QK^T] [V->regs] [ds_write staged -> cur^1]
//   [softmax (raw exp2)] [pa via permlane32_swap] [PV(regs)] [barrier]
__global__ __launch_bounds__(256, 2) void attn_kernel(
    const _Float16* __restrict__ Q, const _Float16* __restrict__ Kf,
    const _Float16* __restrict__ Vf, _Float16* __restrict__ AO)
{
    __shared__ alignas(16) _Float16 kvbuf[2][24 * 512];  // 12 K-frags + 12 V-frags
    __shared__ float tab[4][32];

    const int tid = threadIdx.x;
    const int lane = tid & 63, w = tid >> 6;
    const int l31 = lane & 31, hi = lane >> 5;

    const int B = blockIdx.x;           // 0..511
    const int xcd = B & 7, j = B >> 3;  // 2 bh per XCD -> K/V L2-resident
    const int bh = 2 * xcd + (j >> 5);
    const int qb = j & 31;
    const int q0 = qb * 128 + w * 32;

    const size_t qBase = (size_t)bh * 4096 * 96;
    const _Float16* kfb = Kf + (size_t)bh * 393216;
    const _Float16* vfb = Vf + (size_t)bh * 393216;

    // Q as B-operand fragments (already scaled by LOG2E at QKV epilogue)
    half8 qf[6];
    #pragma unroll
    for (int dch = 0; dch < 6; ++dch)
        qf[dch] = *(const half8*)(Q + qBase + (size_t)(q0 + l31) * 96 + dch * 16 + hi * 8);

    f32x16 o0 = {}, o1 = {}, o2 = {};
    float m = -1e30f, l = 0.f;          // per-lane; lane owns q = lane&31

    // staging: wave w owns frags fbase..fbase+5 of 24 (f<12: K, else V)
    const int fbase = w * 6;
    const _Float16* gbase = ((fbase < 12) ? (kfb + (size_t)fbase * 512)
                                          : (vfb + (size_t)(fbase - 12) * 512)) + lane * 8;

    half8 streg[6], vreg[12];

    // ---- prologue: tile 0 via regs -> LDS buf0 ----
    #pragma unroll
    for (int i = 0; i < 6; ++i)
        streg[i] = *(const half8*)(gbase + i * 512);
    #pragma unroll
    for (int i = 0; i < 6; ++i)
        *(half8*)(&kvbuf[0][(fbase + i) * 512 + lane * 8]) = streg[i];
    __syncthreads();

    int cur = 0;
    for (int t = 0; t < 64; ++t) {
        // ---- issue next-tile global loads early (T14); none needed at t=63 ----
        if (t < 63) {
            const int tn = t + 1;
            #pragma unroll
            for (int i = 0; i < 6; ++i)
                streg[i] = *(const half8*)(gbase + (size_t)tn * 6144 + i * 512);
        }

        const _Float16* kb = &kvbuf[cur][0];
        const _Float16* vb = &kvbuf[cur][12 * 512];

        // ---- S^T = K Q^T (rows=keys, cols=q) ----
        f32x16 s0 = {}, s1 = {};
        __builtin_amdgcn_s_setprio(1);
        #pragma unroll
        for (int dch = 0; dch < 6; ++dch) {
            half8 k0 = *(const half8*)(kb + dch * 512 + lane * 8);
            half8 k1 = *(const half8*)(kb + (6 + dch) * 512 + lane * 8);
            s0 = mfma32(k0, qf[dch], s0);
            s1 = mfma32(k1, qf[dch], s1);
        }
        __builtin_amdgcn_s_setprio(0);

        // ---- V early: LDS -> regs, overlaps softmax VALU below ----
        #pragma unroll
        for (int i = 0; i < 12; ++i)
            vreg[i] = *(const half8*)(vb + i * 512 + lane * 8);

        // ---- write-late staging into the other buffer (no barrier needed:
        //      last reads of kvbuf[cur^1] were in iter t-1, gated by its barrier)
        if (t < 63) {
            #pragma unroll
            for (int i = 0; i < 6; ++i)
                *(half8*)(&kvbuf[cur ^ 1][(fbase + i) * 512 + lane * 8]) = streg[i];
        }

        // ---- in-register online softmax (exp2 domain, raw v_exp), tree max ----
        float mx[8];
        #pragma unroll
        for (int r = 0; r < 8; ++r)
            mx[r] = fmaxf(fmaxf(s0[r], s0[r + 8]), fmaxf(s1[r], s1[r + 8]));
        mx[0] = fmaxf(mx[0], mx[4]); mx[1] = fmaxf(mx[1], mx[5]);
        mx[2] = fmaxf(mx[2], mx[6]); mx[3] = fmaxf(mx[3], mx[7]);
        float lm = fmaxf(fmaxf(mx[0], mx[1]), fmaxf(mx[2], mx[3]));
        float pmax = fmaxf(lm, __shfl_xor(lm, 32));   // R10-proven cross-half reduce
        if (__any(pmax > m + 8.0f)) {          // defer-max (log2 domain, THR=8)
            float mn = fmaxf(m, pmax);
            float al = fast_exp2(m - mn);
            m = mn; l *= al;
            if (hi == 0) tab[w][l31] = al;
            asm volatile("s_waitcnt lgkmcnt(0)" ::: "memory");
            #pragma unroll
            for (int r = 0; r < 16; ++r) {
                float alr = tab[w][(r & 3) + 8 * (r >> 2) + 4 * hi];
                o0[r] *= alr; o1[r] *= alr; o2[r] *= alr;
            }
        }
        float ls = 0.f;
        uint32_t Lp[16];
        #pragma unroll
        for (int kg = 0; kg < 2; ++kg) {
            const f32x16& s = kg ? s1 : s0;
            #pragma unroll
            for (int jg = 0; jg < 4; ++jg) {
                float p0 = fast_exp2(s[4 * jg + 0] - m);
                float p1 = fast_exp2(s[4 * jg + 1] - m);
                float p2 = fast_exp2(s[4 * jg + 2] - m);
                float p3 = fast_exp2(s[4 * jg + 3] - m);
                ls += (p0 + p1) + (p2 + p3);
                Lp[kg * 8 + jg * 2]     = pack_pair(p0, p1);
                Lp[kg * 8 + jg * 2 + 1] = pack_pair(p2, p3);
            }
        }
        l += ls + __shfl_xor(ls, 32);                 // R10-proven cross-half reduce

        // pa[kk]: A-frag row=q(l31), k = kk*16 + hi*8 + e
        half8 pa[4];
        #pragma unroll
        for (int kk = 0; kk < 4; ++kk) {
            uint32_t u0 = Lp[4 * kk], u1 = Lp[4 * kk + 1];
            uint32_t u2 = Lp[4 * kk + 2], u3 = Lp[4 * kk + 3];
            asm("v_permlane32_swap_b32 %0, %1" : "+v"(u0), "+v"(u2));
            asm("v_permlane32_swap_b32 %0, %1" : "+v"(u1), "+v"(u3));
            union { half8 h; uint32_t u[4]; } fr;
            fr.u[0] = u0; fr.u[1] = u1; fr.u[2] = u2; fr.u[3] = u3;
            pa[kk] = fr.h;
        }

        // ---- O += P @ V (V from registers) ----
        __builtin_amdgcn_s_setprio(1);
        #pragma unroll
        for (int kk = 0; kk < 4; ++kk) {
            o0 = mfma32(pa[kk], vreg[kk * 3 + 0], o0);
            o1 = mfma32(pa[kk], vreg[kk * 3 + 1], o1);
            o2 = mfma32(pa[kk], vreg[kk * 3 + 2], o2);
        }
        __builtin_amdgcn_s_setprio(0);

        __syncthreads();   // staged tile visible; all reads of cur done
        cur ^= 1;
    }

    // ---- epilogue: O * SCALE/l -> AO[b][n][h*96+d] (f16) ----
    if (hi == 0) tab[w][l31] = l;
    asm volatile("s_waitcnt lgkmcnt(0)" ::: "memory");
    const int b = bh >> 3, h = bh & 7;
    #pragma unroll
    for (int r = 0; r < 16; ++r) {
        int qrow = (r & 3) + 8 * (r >> 2) + 4 * hi;
        float inv = SCALE / tab[w][qrow];
        int n = q0 + qrow;
        size_t base = ((size_t)(b * 4096 + n)) * 768 + h * 96 + l31;
        AO[base]      = (_Float16)(o0[r] * inv);
        AO[base + 32] = (_Float16)(o1[r] * inv);
        AO[base + 64] = (_Float16)(o2[r] * inv);
    }
}

// ---------------- launch ----------------

extern "C" void kernel_launch(void* const* d_in, const int* in_sizes, int n_in,
                              void* d_out, int out_size, void* d_ws, size_t ws_size,
                              hipStream_t stream) {
    const float* x  = (const float*)d_in[0];
    const float* Wq = (const float*)d_in[1];
    const float* bq = (const float*)d_in[2];
    const float* Wk = (const float*)d_in[3];
    const float* bk = (const float*)d_in[4];
    const float* Wv = (const float*)d_in[5];
    const float* bv = (const float*)d_in[6];
    const float* Wo = (const float*)d_in[7];
    const float* bo = (const float*)d_in[8];
    float* out = (float*)d_out;

    char* ws = (char*)d_ws;
    _Float16* xb   = (_Float16*)(ws);                 // 12,582,912  (reused as AO)
    _Float16* wqkv = (_Float16*)(ws + 12582912);      //  3,538,944
    _Float16* wot  = (_Float16*)(ws + 16121856);      //  1,179,648
    float*    bqkv = (float*)   (ws + 17301504);      //      9,216
    _Float16* Qb   = (_Float16*)(ws + 17310720);      // 12,582,912
    _Float16* Kfb  = (_Float16*)(ws + 29893632);      // 12,582,912
    _Float16* Vfb  = (_Float16*)(ws + 42476544);      // 12,582,912  -> total 55,059,456 B
    _Float16* AO   = xb;  // xb dead after QKV GEMM

    prep_all<<<6729, 256, 0, stream>>>(x, xb, Wq, Wk, Wv, Wo, wqkv, wot, bq, bk, bv, bqkv);

    // QKV: M=8192, N=2304 (18 x 64 tiles of 128x128)
    gemm_kernel<<<dim3(18, 64), 256, 0, stream>>>(xb, wqkv, bqkv, 0, Qb, Kfb, Vfb, nullptr);

    attn_kernel<<<512, 256, 0, stream>>>(Qb, Kfb, Vfb, AO);

    // out-proj: M=8192, N=768 (6 x 64 tiles)
    gemm_kernel<<<dim3(6, 64), 256, 0, stream>>>(AO, wot, bo, 1, nullptr, nullptr, nullptr, out);
}

// Round 20
// 244.019 us; speedup vs baseline: 1.0064x; 1.0064x over previous
//
#include <hip/hip_runtime.h>
#include <hip/hip_fp16.h>

// MHA forward, fp16 MFMA pipeline.
// B=2, N=4096, E=768, H=8, D=96.  SCALE applied AFTER softmax (faithful to ref).
// Round 20: byte-identical revert to R18 (best measured: 244.6us).
//   R19's single-barrier variant was slightly negative (attn 137.5->140.1):
//   the barrier was nearly free (waves co-arrive), and the hoisted ds_writes
//   added lgkmcnt pressure in the V-read->PV window. Final configuration:
//   - prep fused into one launch
//   - GEMM: 128x128 tile, BK=64, global_load_lds w16, fragment-linear LDS
//   - attn: 4 waves x 32q, swapped QK^T 32x32 MFMA, in-register exp2 softmax
//     (raw v_exp), cvt_pkrtz P-pack, permlane32_swap pa-build, reg-staged
//     write-late double buffer, 2 barriers/tile, t<63 prefetch guard.

typedef _Float16 half8 __attribute__((ext_vector_type(8)));
typedef _Float16 half4 __attribute__((ext_vector_type(4)));
typedef float   float4_ __attribute__((ext_vector_type(4)));
typedef float   f32x16 __attribute__((ext_vector_type(16)));

#define SCALE 0.102062072615966f  // 96^-0.5
#define LOG2E 1.44269504088896340736f

__device__ __forceinline__ float4_ mfma16(half8 a, half8 b, float4_ c) {
    return __builtin_amdgcn_mfma_f32_16x16x32_f16(a, b, c, 0, 0, 0);
}
__device__ __forceinline__ f32x16 mfma32(half8 a, half8 b, f32x16 c) {
    return __builtin_amdgcn_mfma_f32_32x32x16_f16(a, b, c, 0, 0, 0);
}
__device__ __forceinline__ void gload16(const _Float16* g, _Float16* l) {
    __builtin_amdgcn_global_load_lds(
        (const __attribute__((address_space(1))) void*)g,
        (__attribute__((address_space(3))) void*)l, 16, 0, 0);
}

// Raw v_exp_f32: single transcendental, no denormal-guard sequence (R10-verified).
__device__ __forceinline__ float fast_exp2(float x) {
#if __has_builtin(__builtin_amdgcn_exp2f)
    return __builtin_amdgcn_exp2f(x);
#else
    float r;
    asm("v_exp_f32 %0, %1" : "=v"(r) : "v"(x));
    return r;
#endif
}

// Packed f32 pair -> f16x2 in one VALU op (RTZ; fine at 1e-2 tol).
__device__ __forceinline__ uint32_t pack_pair(float a, float b) {
#if __has_builtin(__builtin_amdgcn_cvt_pkrtz)
    auto h = __builtin_amdgcn_cvt_pkrtz(a, b);
    union { decltype(h) v; uint32_t u; } c;
    c.v = h;
    return c.u;
#else
    union { _Float16 h[2]; uint32_t u; } c;
    c.h[0] = (_Float16)a; c.h[1] = (_Float16)b;
    return c.u;
#endif
}

// ---------------- fused prep kernel ----------------
// blocks [0,6144): cast x -> f16.  [6144,6720): W transpose.  [6720,6729): bias concat.
__global__ void prep_all(const float* __restrict__ x, _Float16* __restrict__ xb,
                         const float* __restrict__ Wq, const float* __restrict__ Wk,
                         const float* __restrict__ Wv, const float* __restrict__ Wo,
                         _Float16* __restrict__ wqkv, _Float16* __restrict__ wot,
                         const float* __restrict__ bq, const float* __restrict__ bk,
                         const float* __restrict__ bv, float* __restrict__ bqkv) {
    __shared__ float tile[64][65];
    const int bid = blockIdx.x;
    const int t = threadIdx.x;
    if (bid < 6144) {                       // cast_x: 6144*256 float4 = 8192*768 floats
        int i = bid * 256 + t;
        float4_ v = ((const float4_*)x)[i];
        half4 h = { (_Float16)v[0], (_Float16)v[1], (_Float16)v[2], (_Float16)v[3] };
        ((half4*)xb)[i] = h;
    } else if (bid < 6720) {                // prep_w: 576 = 4 mats * 12 * 12
        const int wb = bid - 6144;
        const int mat = wb / 144, rem = wb % 144;
        const int kt = rem / 12, ct = rem % 12;
        const float* W = (mat == 0) ? Wq : (mat == 1) ? Wk : (mat == 2) ? Wv : Wo;
        const int k0 = kt * 64, c0 = ct * 64;
        const int lr = t >> 4, lc = (t & 15) * 4;
        #pragma unroll
        for (int i = 0; i < 4; ++i) {
            float4_ v = *(const float4_*)(W + (size_t)(k0 + i * 16 + lr) * 768 + c0 + lc);
            tile[i * 16 + lr][lc + 0] = v[0];
            tile[i * 16 + lr][lc + 1] = v[1];
            tile[i * 16 + lr][lc + 2] = v[2];
            tile[i * 16 + lr][lc + 3] = v[3];
        }
        __syncthreads();
        const int cr = t >> 2, kq = (t & 3) * 16;
        _Float16* dst = (mat < 3) ? (wqkv + ((size_t)(mat * 768 + c0 + cr)) * 768 + k0 + kq)
                                  : (wot  + ((size_t)(c0 + cr)) * 768 + k0 + kq);
        half8 h0, h1;
        #pragma unroll
        for (int j = 0; j < 8; ++j) {
            h0[j] = (_Float16)tile[kq + j][cr];
            h1[j] = (_Float16)tile[kq + 8 + j][cr];
        }
        *(half8*)dst = h0;
        *(half8*)(dst + 8) = h1;
    } else {                                // prep_bias: 9 blocks -> 2304 floats
        int i = (bid - 6720) * 256 + t;
        float v = (i < 768) ? bq[i] : (i < 1536) ? bk[i - 768] : bv[i - 1536];
        bqkv[i] = v;
    }
}

// ---------------- GEMM: C = A(8192x768) @ Bt^T + bias, 128x128 tile, BK=64 ----
__global__ __launch_bounds__(256, 2) void gemm_kernel(
    const _Float16* __restrict__ A, const _Float16* __restrict__ Bt,
    const float* __restrict__ bias, int mode,
    _Float16* __restrict__ Qo, _Float16* __restrict__ Ko, _Float16* __restrict__ Vto,
    float* __restrict__ out)
{
    __shared__ alignas(16) _Float16 Af[16 * 512];   // 16 frags (mi 0..7, kc 0..1)
    __shared__ alignas(16) _Float16 Bf[16 * 512];
    const int tid = threadIdx.x;
    const int lane = tid & 63, w = tid >> 6;
    const int wm = w >> 1, wn = w & 1;
    const int l15 = lane & 15, l4 = lane >> 4;
    const int m0 = blockIdx.y * 128;
    const int n0 = blockIdx.x * 128;

    const _Float16* gs[8];
    _Float16* ld[8];
    #pragma unroll
    for (int i = 0; i < 8; ++i) {
        int f = (w & 1) * 8 + i;
        int rg = f >> 1, kc = f & 1;
        int r0 = ((w < 2) ? m0 : n0) + rg * 16;
        gs[i] = ((w < 2) ? A : Bt) + (size_t)(r0 + l15) * 768 + kc * 32 + l4 * 8;
        ld[i] = ((w < 2) ? Af : Bf) + f * 512;
    }

    float4_ acc[4][4] = {};

    for (int k0 = 0; k0 < 768; k0 += 64) {
        #pragma unroll
        for (int i = 0; i < 8; ++i)
            gload16(gs[i] + k0, ld[i]);
        __syncthreads();
        #pragma unroll
        for (int kc = 0; kc < 2; ++kc) {
            half8 bfr[4];
            #pragma unroll
            for (int nt = 0; nt < 4; ++nt)
                bfr[nt] = *(const half8*)(Bf + (size_t)(((wn * 4 + nt) * 2 + kc) * 512 + lane * 8));
            #pragma unroll
            for (int mt = 0; mt < 4; ++mt) {
                half8 afr = *(const half8*)(Af + (size_t)(((wm * 4 + mt) * 2 + kc) * 512 + lane * 8));
                #pragma unroll
                for (int nt = 0; nt < 4; ++nt)
                    acc[mt][nt] = mfma16(afr, bfr[nt], acc[mt][nt]);
            }
        }
        __syncthreads();
    }

    #pragma unroll
    for (int mt = 0; mt < 4; ++mt)
    #pragma unroll
    for (int nt = 0; nt < 4; ++nt) {
        int gc = n0 + wn * 64 + nt * 16 + l15;
        float bv_ = bias[gc];
        #pragma unroll
        for (int r = 0; r < 4; ++r) {
            int gm = m0 + wm * 64 + mt * 16 + l4 * 4 + r;
            float val = acc[mt][nt][r] + bv_;
            if (mode == 1) {
                out[(size_t)gm * 768 + gc] = val;
            } else {
                int b = gm >> 12, n = gm & 4095;
                if (gc < 768) {
                    int h = gc / 96, d = gc % 96;
                    Qo[(((size_t)(b * 8 + h)) * 4096 + n) * 96 + d] = (_Float16)(val * LOG2E);
                } else if (gc < 1536) {
                    int c = gc - 768, h = c / 96, d = c % 96;
                    int bh = b * 8 + h;
                    size_t idx = (((size_t)bh * 128 + (n >> 5)) * 6 + (d >> 4)) * 512
                               + (size_t)((d >> 3) & 1) * 256 + (size_t)(n & 31) * 8 + (d & 7);
                    Ko[idx] = (_Float16)val;
                } else {
                    int c = gc - 1536, h = c / 96, d = c % 96;
                    int bh = b * 8 + h;
                    size_t idx = (((size_t)bh * 64 + (n >> 6)) * 12 + ((n >> 4) & 3) * 3 + (d >> 5)) * 512
                               + (size_t)((n >> 3) & 1) * 256 + (size_t)(d & 31) * 8 + (n & 7);
                    Vto[idx] = (_Float16)val;
                }
            }
        }
    }
}

// ---------------- flash attention: 4 waves x 32 q, KV tile 64 ----------------
// 512 blocks (2/CU, 2 waves/SIMD). R16 skeleton (best): per tile
//   [issue next-tile global->regs] [QK^T] [V->regs] [softmax (raw exp2)]
//   [pa via permlane32_swap] [PV(regs)] [barrier] [ds_write staged] [barrier]
// t=63 prefetch/ds_write skipped (R17-verified neutral-to-positive).
__global__ __launch_bounds__(256, 2) void attn_kernel(
    const _Float16* __restrict__ Q, const _Float16* __restrict__ Kf,
    const _Float16* __restrict__ Vf, _Float16* __restrict__ AO)
{
    __shared__ alignas(16) _Float16 kvbuf[2][24 * 512];  // 12 K-frags + 12 V-frags
    __shared__ float tab[4][32];

    const int tid = threadIdx.x;
    const int lane = tid & 63, w = tid >> 6;
    const int l31 = lane & 31, hi = lane >> 5;

    const int B = blockIdx.x;           // 0..511
    const int xcd = B & 7, j = B >> 3;  // 2 bh per XCD -> K/V L2-resident
    const int bh = 2 * xcd + (j >> 5);
    const int qb = j & 31;
    const int q0 = qb * 128 + w * 32;

    const size_t qBase = (size_t)bh * 4096 * 96;
    const _Float16* kfb = Kf + (size_t)bh * 393216;
    const _Float16* vfb = Vf + (size_t)bh * 393216;

    // Q as B-operand fragments (already scaled by LOG2E at QKV epilogue)
    half8 qf[6];
    #pragma unroll
    for (int dch = 0; dch < 6; ++dch)
        qf[dch] = *(const half8*)(Q + qBase + (size_t)(q0 + l31) * 96 + dch * 16 + hi * 8);

    f32x16 o0 = {}, o1 = {}, o2 = {};
    float m = -1e30f, l = 0.f;          // per-lane; lane owns q = lane&31

    // staging: wave w owns frags fbase..fbase+5 of 24 (f<12: K, else V)
    const int fbase = w * 6;
    const _Float16* gbase = ((fbase < 12) ? (kfb + (size_t)fbase * 512)
                                          : (vfb + (size_t)(fbase - 12) * 512)) + lane * 8;

    half8 streg[6], vreg[12];

    // ---- prologue: tile 0 via regs -> LDS buf0 ----
    #pragma unroll
    for (int i = 0; i < 6; ++i)
        streg[i] = *(const half8*)(gbase + i * 512);
    #pragma unroll
    for (int i = 0; i < 6; ++i)
        *(half8*)(&kvbuf[0][(fbase + i) * 512 + lane * 8]) = streg[i];
    __syncthreads();

    int cur = 0;
    for (int t = 0; t < 64; ++t) {
        // ---- issue next-tile global loads early (T14); none needed at t=63 ----
        if (t < 63) {
            const int tn = t + 1;
            #pragma unroll
            for (int i = 0; i < 6; ++i)
                streg[i] = *(const half8*)(gbase + (size_t)tn * 6144 + i * 512);
        }

        const _Float16* kb = &kvbuf[cur][0];
        const _Float16* vb = &kvbuf[cur][12 * 512];

        // ---- S^T = K Q^T (rows=keys, cols=q) ----
        f32x16 s0 = {}, s1 = {};
        __builtin_amdgcn_s_setprio(1);
        #pragma unroll
        for (int dch = 0; dch < 6; ++dch) {
            half8 k0 = *(const half8*)(kb + dch * 512 + lane * 8);
            half8 k1 = *(const half8*)(kb + (6 + dch) * 512 + lane * 8);
            s0 = mfma32(k0, qf[dch], s0);
            s1 = mfma32(k1, qf[dch], s1);
        }
        __builtin_amdgcn_s_setprio(0);

        // ---- V early: LDS -> regs, overlaps softmax VALU below ----
        #pragma unroll
        for (int i = 0; i < 12; ++i)
            vreg[i] = *(const half8*)(vb + i * 512 + lane * 8);

        // ---- in-register online softmax (exp2 domain, raw v_exp), tree max ----
        float mx[8];
        #pragma unroll
        for (int r = 0; r < 8; ++r)
            mx[r] = fmaxf(fmaxf(s0[r], s0[r + 8]), fmaxf(s1[r], s1[r + 8]));
        mx[0] = fmaxf(mx[0], mx[4]); mx[1] = fmaxf(mx[1], mx[5]);
        mx[2] = fmaxf(mx[2], mx[6]); mx[3] = fmaxf(mx[3], mx[7]);
        float lm = fmaxf(fmaxf(mx[0], mx[1]), fmaxf(mx[2], mx[3]));
        float pmax = fmaxf(lm, __shfl_xor(lm, 32));   // R10-proven cross-half reduce
        if (__any(pmax > m + 8.0f)) {          // defer-max (log2 domain, THR=8)
            float mn = fmaxf(m, pmax);
            float al = fast_exp2(m - mn);
            m = mn; l *= al;
            if (hi == 0) tab[w][l31] = al;
            asm volatile("s_waitcnt lgkmcnt(0)" ::: "memory");
            #pragma unroll
            for (int r = 0; r < 16; ++r) {
                float alr = tab[w][(r & 3) + 8 * (r >> 2) + 4 * hi];
                o0[r] *= alr; o1[r] *= alr; o2[r] *= alr;
            }
        }
        float ls = 0.f;
        uint32_t Lp[16];
        #pragma unroll
        for (int kg = 0; kg < 2; ++kg) {
            const f32x16& s = kg ? s1 : s0;
            #pragma unroll
            for (int jg = 0; jg < 4; ++jg) {
                float p0 = fast_exp2(s[4 * jg + 0] - m);
                float p1 = fast_exp2(s[4 * jg + 1] - m);
                float p2 = fast_exp2(s[4 * jg + 2] - m);
                float p3 = fast_exp2(s[4 * jg + 3] - m);
                ls += (p0 + p1) + (p2 + p3);
                Lp[kg * 8 + jg * 2]     = pack_pair(p0, p1);
                Lp[kg * 8 + jg * 2 + 1] = pack_pair(p2, p3);
            }
        }
        l += ls + __shfl_xor(ls, 32);                 // R10-proven cross-half reduce

        // pa[kk]: A-frag row=q(l31), k = kk*16 + hi*8 + e
        half8 pa[4];
        #pragma unroll
        for (int kk = 0; kk < 4; ++kk) {
            uint32_t u0 = Lp[4 * kk], u1 = Lp[4 * kk + 1];
            uint32_t u2 = Lp[4 * kk + 2], u3 = Lp[4 * kk + 3];
            asm("v_permlane32_swap_b32 %0, %1" : "+v"(u0), "+v"(u2));
            asm("v_permlane32_swap_b32 %0, %1" : "+v"(u1), "+v"(u3));
            union { half8 h; uint32_t u[4]; } fr;
            fr.u[0] = u0; fr.u[1] = u1; fr.u[2] = u2; fr.u[3] = u3;
            pa[kk] = fr.h;
        }

        // ---- O += P @ V (V from registers) ----
        __builtin_amdgcn_s_setprio(1);
        #pragma unroll
        for (int kk = 0; kk < 4; ++kk) {
            o0 = mfma32(pa[kk], vreg[kk * 3 + 0], o0);
            o1 = mfma32(pa[kk], vreg[kk * 3 + 1], o1);
            o2 = mfma32(pa[kk], vreg[kk * 3 + 2], o2);
        }
        __builtin_amdgcn_s_setprio(0);

        // ---- write-late staging into the other buffer ----
        __syncthreads();   // all waves done reading kvbuf[cur]
        if (t < 63) {
            #pragma unroll
            for (int i = 0; i < 6; ++i)
                *(half8*)(&kvbuf[cur ^ 1][(fbase + i) * 512 + lane * 8]) = streg[i];
        }
        __syncthreads();   // staged tile visible to all
        cur ^= 1;
    }

    // ---- epilogue: O * SCALE/l -> AO[b][n][h*96+d] (f16) ----
    if (hi == 0) tab[w][l31] = l;
    asm volatile("s_waitcnt lgkmcnt(0)" ::: "memory");
    const int b = bh >> 3, h = bh & 7;
    #pragma unroll
    for (int r = 0; r < 16; ++r) {
        int qrow = (r & 3) + 8 * (r >> 2) + 4 * hi;
        float inv = SCALE / tab[w][qrow];
        int n = q0 + qrow;
        size_t base = ((size_t)(b * 4096 + n)) * 768 + h * 96 + l31;
        AO[base]      = (_Float16)(o0[r] * inv);
        AO[base + 32] = (_Float16)(o1[r] * inv);
        AO[base + 64] = (_Float16)(o2[r] * inv);
    }
}

// ---------------- launch ----------------

extern "C" void kernel_launch(void* const* d_in, const int* in_sizes, int n_in,
                              void* d_out, int out_size, void* d_ws, size_t ws_size,
                              hipStream_t stream) {
    const float* x  = (const float*)d_in[0];
    const float* Wq = (const float*)d_in[1];
    const float* bq = (const float*)d_in[2];
    const float* Wk = (const float*)d_in[3];
    const float* bk = (const float*)d_in[4];
    const float* Wv = (const float*)d_in[5];
    const float* bv = (const float*)d_in[6];
    const float* Wo = (const float*)d_in[7];
    const float* bo = (const float*)d_in[8];
    float* out = (float*)d_out;

    char* ws = (char*)d_ws;
    _Float16* xb   = (_Float16*)(ws);                 // 12,582,912  (reused as AO)
    _Float16* wqkv = (_Float16*)(ws + 12582912);      //  3,538,944
    _Float16* wot  = (_Float16*)(ws + 16121856);      //  1,179,648
    float*    bqkv = (float*)   (ws + 17301504);      //      9,216
    _Float16* Qb   = (_Float16*)(ws + 17310720);      // 12,582,912
    _Float16* Kfb  = (_Float16*)(ws + 29893632);      // 12,582,912
    _Float16* Vfb  = (_Float16*)(ws + 42476544);      // 12,582,912  -> total 55,059,456 B
    _Float16* AO   = xb;  // xb dead after QKV GEMM

    prep_all<<<6729, 256, 0, stream>>>(x, xb, Wq, Wk, Wv, Wo, wqkv, wot, bq, bk, bv, bqkv);

    // QKV: M=8192, N=2304 (18 x 64 tiles of 128x128)
    gemm_kernel<<<dim3(18, 64), 256, 0, stream>>>(xb, wqkv, bqkv, 0, Qb, Kfb, Vfb, nullptr);

    attn_kernel<<<512, 256, 0, stream>>>(Qb, Kfb, Vfb, AO);

    // out-proj: M=8192, N=768 (6 x 64 tiles)
    gemm_kernel<<<dim3(6, 64), 256, 0, stream>>>(AO, wot, bo, 1, nullptr, nullptr, nullptr, out);
}